// Round 4
// baseline (576.291 us; speedup 1.0000x reference)
//
#include <hip/hip_runtime.h>

// DE3: out[0] = B * (8 + sum_i p_i*log2(p_i)), p_i = hist_i / (H*W),
// hist over floor(img) in [0,256), img is (16,2048,2048) fp32 = 268 MB.
// Memory-bound streaming reduction: floor ~43 us @ 6.3 TB/s.
//
// R4: identical to R3 (R3 never ran - GPU acquisition timeout).
// Fused hist+entropy via last-block ticket (device-scope atomics, m20),
// 2x unrolled nontemporal float4 loads (clang ext_vector type).

#define NBINS 256
#define HIST_BLOCKS 2048
#define HIST_THREADS 256

typedef float f32x4 __attribute__((ext_vector_type(4)));

__global__ void zero_hist(unsigned int* __restrict__ hist) {
    // 256 bins + [256] = completion ticket. d_ws is re-poisoned to 0xAA
    // before every timed launch, so this must run every call.
    hist[threadIdx.x] = 0u;
    if (threadIdx.x == 0) hist[NBINS] = 0u;
}

__global__ __launch_bounds__(HIST_THREADS) void hist_entropy_kernel(
        const float* __restrict__ img,
        unsigned int* __restrict__ ghist,
        float* __restrict__ out,
        int n_vec4, long long n_total,
        float B, float inv_temp) {
    // One private LDS histogram per wave (4 waves/block): random uniform
    // bins -> ~2 lanes/bank on ds_add, which is free (m136).
    __shared__ unsigned int lhist[4][NBINS];
    const int t = threadIdx.x;
    const int wave = t >> 6;

    for (int i = t; i < 4 * NBINS; i += HIST_THREADS)
        ((unsigned int*)lhist)[i] = 0u;
    __syncthreads();

    const f32x4* __restrict__ img4 = (const f32x4*)img;
    const int tid = blockIdx.x * HIST_THREADS + t;
    const int stride = gridDim.x * HIST_THREADS;

    // 2x-unrolled grid-stride: two independent 16B nontemporal loads in
    // flight before the LDS-atomic burst (read-once data, skip L2 reuse).
    int i = tid;
    for (; i + stride < n_vec4; i += 2 * stride) {
        f32x4 a = __builtin_nontemporal_load(&img4[i]);
        f32x4 b = __builtin_nontemporal_load(&img4[i + stride]);
        #pragma unroll
        for (int k = 0; k < 4; ++k)
            if (a[k] >= 0.0f && a[k] < 256.0f)
                atomicAdd(&lhist[wave][(int)a[k]], 1u);
        #pragma unroll
        for (int k = 0; k < 4; ++k)
            if (b[k] >= 0.0f && b[k] < 256.0f)
                atomicAdd(&lhist[wave][(int)b[k]], 1u);
    }
    for (; i < n_vec4; i += stride) {
        f32x4 a = __builtin_nontemporal_load(&img4[i]);
        #pragma unroll
        for (int k = 0; k < 4; ++k)
            if (a[k] >= 0.0f && a[k] < 256.0f)
                atomicAdd(&lhist[wave][(int)a[k]], 1u);
    }
    // Scalar tail (n_total % 4): no-op at this problem size.
    for (long long j = 4LL * n_vec4 + tid; j < n_total; j += stride) {
        float v = img[j];
        if (v >= 0.0f && v < 256.0f) atomicAdd(&lhist[wave][(int)v], 1u);
    }

    __syncthreads();
    unsigned int s = lhist[0][t] + lhist[1][t] + lhist[2][t] + lhist[3][t];
    if (s) atomicAdd(&ghist[t], s);

    // Last-block ticket: device-scope fence so our ghist adds are visible,
    // then the last block to increment the ticket computes the entropy.
    __threadfence();
    __shared__ unsigned int ticket;
    if (t == 0) ticket = atomicAdd(&ghist[NBINS], 1u);
    __syncthreads();
    if (ticket == (unsigned int)(gridDim.x - 1)) {
        // Atomic read (add 0) bypasses stale caches across XCDs.
        unsigned int c = atomicAdd(&ghist[t], 0u);
        float term = 0.0f;
        if (c > 0u) {
            float p = (float)c * inv_temp;
            term = p * __log2f(p);
        }
        #pragma unroll
        for (int off = 32; off > 0; off >>= 1)
            term += __shfl_down(term, off, 64);
        __shared__ float wsum[4];
        if ((t & 63) == 0) wsum[t >> 6] = term;
        __syncthreads();
        if (t == 0) {
            float ssum = wsum[0] + wsum[1] + wsum[2] + wsum[3];
            out[0] = B * (8.0f + ssum);  // res = -ssum
        }
    }
}

extern "C" void kernel_launch(void* const* d_in, const int* in_sizes, int n_in,
                              void* d_out, int out_size, void* d_ws, size_t ws_size,
                              hipStream_t stream) {
    const float* img = (const float*)d_in[0];
    float* out = (float*)d_out;
    unsigned int* ghist = (unsigned int*)d_ws;  // 257 u32 of scratch

    const long long n = (long long)in_sizes[0];   // B*H*W = 67,108,864
    const long long HW = 2048LL * 2048LL;         // temp = H*W (fixed shape)
    const float B = (float)(n / HW);              // 16
    const float inv_temp = 1.0f / (float)HW;
    const int n_vec4 = (int)(n / 4);

    zero_hist<<<dim3(1), dim3(NBINS), 0, stream>>>(ghist);
    hist_entropy_kernel<<<dim3(HIST_BLOCKS), dim3(HIST_THREADS), 0, stream>>>(
        img, ghist, out, n_vec4, n, B, inv_temp);
}